// Round 5
// baseline (1254.351 us; speedup 1.0000x reference)
//
#include <hip/hip_runtime.h>
#include <hip/hip_fp16.h>
#include <hip/hip_bf16.h>

// LightGCN propagation on MI355X (gfx950).
// out = (h0 + A*h0 + A^2*h0 + A^3*h0)/4, A = COO(edge_row, edge_col, edge_val)
// Round 5 (= round 4 + compile fix: nontemporal store needs native vector
// type, not HIP_vector_type<float,4>):
//  - scatter was line-eviction bound (312 MB HBM writes for 40 MB payload:
//    300k frontier lines >> 4 MB/XCD L2). Two-stage: bucket scatter (9375
//    buckets -> 600 KB frontier, L2-coalesced) + per-bucket LDS-cursor CSR.
//  - spmm was issue-bound (2 B/lane gathers). New layout: 16 lanes x 8 B per
//    row, 4 edges in flight, shfl_xor reduction.

#define NUM_USERS 200000
#define NUM_ITEMS 100000
#define N_NODES   300000
#define EMB_DIM   64
#define NNZ       5000000

#define ROWS_PER_BUCKET 32
#define N_BUCKETS       (N_NODES / ROWS_PER_BUCKET)   // 9375 exactly

#define SCAN_TILE 1024
#define NTILES    ((N_NODES + SCAN_TILE - 1) / SCAN_TILE)   // 293

typedef unsigned long long ull;
typedef float fx4 __attribute__((ext_vector_type(4)));   // native vec for nt-store

// ---------------------------------------------------------------------------
// init: out = ego (fp32), h = ego (fp16, 4 dims packed per uint2)
// ---------------------------------------------------------------------------
__global__ void init_kernel(const float4* __restrict__ user_emb,
                            const float4* __restrict__ item_emb,
                            uint2* __restrict__ h16,
                            float4* __restrict__ out) {
    const int n4 = N_NODES * (EMB_DIM / 4);
    int idx = blockIdx.x * blockDim.x + threadIdx.x;
    if (idx >= n4) return;
    const int user4 = NUM_USERS * (EMB_DIM / 4);
    float4 v = (idx < user4) ? user_emb[idx] : item_emb[idx - user4];
    out[idx] = v;
    __half2 p0 = __floats2half2_rn(v.x, v.y);
    __half2 p1 = __floats2half2_rn(v.z, v.w);
    uint2 u;
    u.x = *(unsigned int*)&p0;
    u.y = *(unsigned int*)&p1;
    h16[idx] = u;
}

__global__ void zero_int_kernel(int* __restrict__ p, int n) {
    int idx = blockIdx.x * blockDim.x + threadIdx.x;
    if (idx < n) p[idx] = 0;
}

__global__ void hist_kernel(const int* __restrict__ row, int* __restrict__ counts) {
    int i = blockIdx.x * blockDim.x + threadIdx.x;
    if (i < NNZ) atomicAdd(&counts[row[i]], 1);
}

// ---------------------------------------------------------------------------
// 3-phase exclusive scan of per-row counts -> row_ptr[0..N_NODES]
// ---------------------------------------------------------------------------
__global__ void scan_phase1(const int* __restrict__ counts, int* __restrict__ partials) {
    __shared__ int lds[256];
    int tile = blockIdx.x, t = threadIdx.x;
    int idx0 = tile * SCAN_TILE + t * 4;
    int s = 0;
#pragma unroll
    for (int i = 0; i < 4; ++i)
        if (idx0 + i < N_NODES) s += counts[idx0 + i];
    lds[t] = s;
    __syncthreads();
    for (int off = 128; off > 0; off >>= 1) {
        if (t < off) lds[t] += lds[t + off];
        __syncthreads();
    }
    if (t == 0) partials[tile] = lds[0];
}

__global__ void scan_phase2(int* __restrict__ partials) {
    __shared__ int lds[512];
    int t = threadIdx.x;
    lds[t] = (t < NTILES) ? partials[t] : 0;
    __syncthreads();
    for (int off = 1; off < 512; off <<= 1) {
        int v = (t >= off) ? lds[t - off] : 0;
        __syncthreads();
        lds[t] += v;
        __syncthreads();
    }
    if (t < NTILES) partials[t] = (t > 0) ? lds[t - 1] : 0;  // exclusive
}

__global__ void scan_phase3(const int* __restrict__ counts,
                            const int* __restrict__ tile_excl,
                            int* __restrict__ row_ptr) {
    __shared__ int lds[256];
    int tile = blockIdx.x, t = threadIdx.x;
    int idx0 = tile * SCAN_TILE + t * 4;
    int c[4];
#pragma unroll
    for (int i = 0; i < 4; ++i)
        c[i] = (idx0 + i < N_NODES) ? counts[idx0 + i] : 0;
    int s = c[0] + c[1] + c[2] + c[3];
    lds[t] = s;
    __syncthreads();
    for (int off = 1; off < 256; off <<= 1) {
        int v = (t >= off) ? lds[t - off] : 0;
        __syncthreads();
        lds[t] += v;
        __syncthreads();
    }
    int thr_excl = (t > 0) ? lds[t - 1] : 0;
    int base = tile_excl[tile] + thr_excl;
    int run = 0;
#pragma unroll
    for (int i = 0; i < 4; ++i) {
        if (idx0 + i <= N_NODES) row_ptr[idx0 + i] = base + run;
        run += c[i];
    }
}

// ---------------------------------------------------------------------------
// bucket cursors = row_ptr at bucket boundaries
// ---------------------------------------------------------------------------
__global__ void init_cursor_kernel(const int* __restrict__ row_ptr,
                                   int* __restrict__ cursor) {
    int b = blockIdx.x * blockDim.x + threadIdx.x;
    if (b < N_BUCKETS) cursor[b] = row_ptr[b * ROWS_PER_BUCKET];
}

// ---------------------------------------------------------------------------
// stage 1: scatter edges into coarse buckets. 9375 frontier lines (600 KB)
// stay L2-resident -> writes coalesce to ~payload size. Plain (cached) store.
// pack: val:32 | row_local:5 (bits 19-23) | col:19 (bits 0-18)
// ---------------------------------------------------------------------------
__global__ void bucket_scatter_kernel(const int* __restrict__ row,
                                      const int* __restrict__ col,
                                      const float* __restrict__ val,
                                      int* __restrict__ cursor,
                                      ull* __restrict__ tmp) {
    int i = blockIdx.x * blockDim.x + threadIdx.x;
    if (i >= NNZ) return;
    int r = row[i];
    int b = r >> 5;                       // /ROWS_PER_BUCKET
    ull p = ((ull)__float_as_uint(val[i]) << 32)
          | ((unsigned int)(r & 31) << 19)
          | (unsigned int)col[i];
    int pos = atomicAdd(&cursor[b], 1);
    tmp[pos] = p;
}

// ---------------------------------------------------------------------------
// stage 2: one WG per bucket. Coalesced read of the bucket's edges, LDS
// cursors give exact CSR position; writes land inside a ~4 KB window (L2).
// row_local bits are kept in csr entries; spmm masks col with 0x7FFFF.
// ---------------------------------------------------------------------------
__global__ void bucket_to_csr_kernel(const ull* __restrict__ tmp,
                                     const int* __restrict__ row_ptr,
                                     ull* __restrict__ csr) {
    __shared__ int cur[ROWS_PER_BUCKET];
    int b = blockIdx.x;
    int t = threadIdx.x;
    int base = b * ROWS_PER_BUCKET;
    if (t < ROWS_PER_BUCKET) cur[t] = row_ptr[base + t];
    __syncthreads();
    int s = row_ptr[base];
    int e = row_ptr[base + ROWS_PER_BUCKET];
    for (int j = s + t; j < e; j += 256) {
        ull p = tmp[j];
        int rl = (int)((p >> 19) & 31u);
        int pos = atomicAdd(&cur[rl], 1);
        csr[pos] = p;
    }
}

// ---------------------------------------------------------------------------
// pull SpMM: one wave per row. 16 lanes x 4 dims per row, 4 edges (sub-groups)
// in flight. fp16 gathers (8 B/lane), fp32 accumulate, shfl_xor reduction.
// Fused epilogue: y16 = fp16(sum); out = (out + sum) * scale.
// ---------------------------------------------------------------------------
__global__ void spmm_pull_kernel(const int* __restrict__ row_ptr,
                                 const ull* __restrict__ csr,
                                 const __half* __restrict__ x,
                                 __half* __restrict__ y,
                                 float* __restrict__ out,
                                 float scale) {
    int gid  = blockIdx.x * blockDim.x + threadIdx.x;
    int wid  = gid >> 6;
    if (wid >= N_NODES) return;
    int lane = threadIdx.x & 63;
    int sub  = lane >> 4;                 // edge slot 0..3
    int part = lane & 15;                 // dim quarter
    wid = __builtin_amdgcn_readfirstlane(wid);
    int s = row_ptr[wid];
    int e = row_ptr[wid + 1];
    float a0 = 0.f, a1 = 0.f, a2 = 0.f, a3 = 0.f;
    for (int k = s; k < e; k += 4) {
        int kk = k + sub;
        bool valid = kk < e;
        ull p = csr[valid ? kk : (e - 1)];
        float v = valid ? __uint_as_float((unsigned int)(p >> 32)) : 0.f;
        unsigned int c = (unsigned int)p & 0x7FFFFu;
        const __half* xr = x + ((size_t)c << 6) + (part << 2);
        uint2 raw = *(const uint2*)xr;    // 4 halfs
        __half2 h01 = *(__half2*)&raw.x;
        __half2 h23 = *(__half2*)&raw.y;
        float2 f01 = __half22float2(h01);
        float2 f23 = __half22float2(h23);
        a0 += v * f01.x;
        a1 += v * f01.y;
        a2 += v * f23.x;
        a3 += v * f23.y;
    }
    // reduce across the 4 edge sub-groups (lanes L, L^16, L^32, L^48)
    a0 += __shfl_xor(a0, 16, 64);
    a1 += __shfl_xor(a1, 16, 64);
    a2 += __shfl_xor(a2, 16, 64);
    a3 += __shfl_xor(a3, 16, 64);
    a0 += __shfl_xor(a0, 32, 64);
    a1 += __shfl_xor(a1, 32, 64);
    a2 += __shfl_xor(a2, 32, 64);
    a3 += __shfl_xor(a3, 32, 64);
    if (sub == 0) {
        int o = (wid << 6) + (part << 2);
        __half2 y01 = __floats2half2_rn(a0, a1);
        __half2 y23 = __floats2half2_rn(a2, a3);
        uint2 yp;
        yp.x = *(unsigned int*)&y01;
        yp.y = *(unsigned int*)&y23;
        *(uint2*)&y[o] = yp;
        const float4* po = (const float4*)&out[o];
        float4 prev = *po;
        fx4 res;
        res.x = (prev.x + a0) * scale;
        res.y = (prev.y + a1) * scale;
        res.z = (prev.z + a2) * scale;
        res.w = (prev.w + a3) * scale;
        __builtin_nontemporal_store(res, (fx4*)&out[o]);
    }
}

// ---------------------------------------------------------------------------
// fallback (round-1 push path) if ws too small
// ---------------------------------------------------------------------------
__global__ void init32_kernel(const float4* __restrict__ user_emb,
                              const float4* __restrict__ item_emb,
                              float4* __restrict__ h,
                              float4* __restrict__ out) {
    const int n4 = N_NODES * (EMB_DIM / 4);
    int idx = blockIdx.x * blockDim.x + threadIdx.x;
    if (idx >= n4) return;
    const int user4 = NUM_USERS * (EMB_DIM / 4);
    float4 v = (idx < user4) ? user_emb[idx] : item_emb[idx - user4];
    h[idx] = v;
    out[idx] = v;
}
__global__ void zero4_kernel(float4* __restrict__ p) {
    const int n4 = N_NODES * (EMB_DIM / 4);
    int idx = blockIdx.x * blockDim.x + threadIdx.x;
    if (idx < n4) p[idx] = make_float4(0.f, 0.f, 0.f, 0.f);
}
__global__ void spmm_push_kernel(const int* __restrict__ row, const int* __restrict__ col,
                                 const float* __restrict__ val, const float* __restrict__ x,
                                 float* __restrict__ y) {
    unsigned int gid = blockIdx.x * blockDim.x + threadIdx.x;
    unsigned int e = gid >> 6, lane = gid & 63u;
    if (e >= NNZ) return;
    atomicAdd(&y[(unsigned int)row[e] * EMB_DIM + lane],
              val[e] * x[(unsigned int)col[e] * EMB_DIM + lane]);
}
__global__ void acc_kernel(float4* __restrict__ out, const float4* __restrict__ h, float scale) {
    const int n4 = N_NODES * (EMB_DIM / 4);
    int idx = blockIdx.x * blockDim.x + threadIdx.x;
    if (idx >= n4) return;
    float4 o = out[idx], a = h[idx];
    o.x = (o.x + a.x) * scale; o.y = (o.y + a.y) * scale;
    o.z = (o.z + a.z) * scale; o.w = (o.w + a.w) * scale;
    out[idx] = o;
}

extern "C" void kernel_launch(void* const* d_in, const int* in_sizes, int n_in,
                              void* d_out, int out_size, void* d_ws, size_t ws_size,
                              hipStream_t stream) {
    const float* user_emb = (const float*)d_in[0];
    const float* item_emb = (const float*)d_in[1];
    const int*   edge_row = (const int*)d_in[2];
    const int*   edge_col = (const int*)d_in[3];
    const float* edge_val = (const float*)d_in[4];
    float* out = (float*)d_out;

    const size_t H16_BYTES = (size_t)N_NODES * EMB_DIM * sizeof(__half);  // 38.4 MB

    char* ws = (char*)d_ws;
    __half* hA     = (__half*)ws;   ws += H16_BYTES;
    __half* hB     = (__half*)ws;   ws += H16_BYTES;
    ull*   csr     = (ull*)ws;      ws += (size_t)NNZ * 8;
    ull*   tmp     = (ull*)ws;      ws += (size_t)NNZ * 8;
    int*   row_ptr = (int*)ws;      ws += (size_t)(N_NODES + 4) * 4;
    int*   counts  = (int*)ws;      ws += (size_t)N_NODES * 4;   // reused as bucket cursors
    int*   partials= (int*)ws;      ws += 4096;
    const size_t REQUIRED = (size_t)(ws - (char*)d_ws);          // ~159.3 MB

    const int blk     = 256;
    const int n4      = N_NODES * (EMB_DIM / 4);
    const int grid_n4 = (n4 + blk - 1) / blk;
    const int grid_nz = (NNZ + blk - 1) / blk;
    const float scales[3] = {1.0f, 1.0f, 0.25f};

    if (ws_size >= REQUIRED) {
        // ---- build CSR (two-stage bucketed) ----
        zero_int_kernel<<<(N_NODES + blk - 1) / blk, blk, 0, stream>>>(counts, N_NODES);
        hist_kernel<<<grid_nz, blk, 0, stream>>>(edge_row, counts);
        scan_phase1<<<NTILES, 256, 0, stream>>>(counts, partials);
        scan_phase2<<<1, 512, 0, stream>>>(partials);
        scan_phase3<<<NTILES, 256, 0, stream>>>(counts, partials, row_ptr);
        int* cursor = counts;  // counts no longer needed after scan
        init_cursor_kernel<<<(N_BUCKETS + blk - 1) / blk, blk, 0, stream>>>(row_ptr, cursor);
        bucket_scatter_kernel<<<grid_nz, blk, 0, stream>>>(edge_row, edge_col, edge_val,
                                                           cursor, tmp);
        bucket_to_csr_kernel<<<N_BUCKETS, 256, 0, stream>>>(tmp, row_ptr, csr);
        // ---- propagate (fp16 h, fp32 out accumulation) ----
        init_kernel<<<grid_n4, blk, 0, stream>>>(
            (const float4*)user_emb, (const float4*)item_emb, (uint2*)hA, (float4*)out);
        __half* h = hA; __half* hn = hB;
        const int grid_sp = (int)(((long long)N_NODES * 64) / blk);  // 75,000
        for (int layer = 0; layer < 3; ++layer) {
            spmm_pull_kernel<<<grid_sp, blk, 0, stream>>>(
                row_ptr, csr, h, hn, out, scales[layer]);
            __half* t = h; h = hn; hn = t;
        }
    } else {
        // fallback: fp32 push path (needs only 2 * 76.8 MB)
        float* hA32 = (float*)d_ws;
        float* hB32 = hA32 + (size_t)N_NODES * EMB_DIM;
        init32_kernel<<<grid_n4, blk, 0, stream>>>(
            (const float4*)user_emb, (const float4*)item_emb, (float4*)hA32, (float4*)out);
        float* h = hA32; float* hn = hB32;
        const int grid_sp = (int)(((long long)NNZ * 64) / blk);
        for (int layer = 0; layer < 3; ++layer) {
            zero4_kernel<<<grid_n4, blk, 0, stream>>>((float4*)hn);
            spmm_push_kernel<<<grid_sp, blk, 0, stream>>>(edge_row, edge_col, edge_val, h, hn);
            acc_kernel<<<grid_n4, blk, 0, stream>>>((float4*)out, (const float4*)hn, scales[layer]);
            float* t = h; h = hn; hn = t;
        }
    }
}